// Round 6
// baseline (351.123 us; speedup 1.0000x reference)
//
#include <hip/hip_runtime.h>
#include <cstdint>
#include <cstddef>

#define AS1 __attribute__((address_space(1)))
#define AS3 __attribute__((address_space(3)))

using half8  = __attribute__((ext_vector_type(8))) _Float16;
using half4v = __attribute__((ext_vector_type(4))) _Float16;
using half2v = __attribute__((ext_vector_type(2))) _Float16;
using f32x4  = __attribute__((ext_vector_type(4))) float;

// ---------- fused prep kernel ----------
// [0,8192):        x -> fp16 (16.8M elems, 8/thread)
// [8192,11264):    Bt 1536x512 fp16 (rows: q|k|v projection weights)
// [11264,12288):   Wo -> fp16 512x512
// [12288,12304):   twiddles (4096: W_4096^p)
// [12304,12310):   bias concat (1536)
__global__ void prep_all_kernel(const float* __restrict__ x,
                                const float* __restrict__ Wq, const float* __restrict__ Wk,
                                const float* __restrict__ Wv, const float* __restrict__ Wo,
                                const float* __restrict__ bq, const float* __restrict__ bk,
                                const float* __restrict__ bv,
                                _Float16* __restrict__ xh, _Float16* __restrict__ Bt,
                                _Float16* __restrict__ WoH,
                                float2* __restrict__ tw, float* __restrict__ bias) {
    const int bid = blockIdx.x;
    const int tid = threadIdx.x;
    if (bid < 8192) {
        int i = (bid * 256 + tid) * 8;
        float4 v0 = *(const float4*)(x + i);
        float4 v1 = *(const float4*)(x + i + 4);
        half8 h;
        h[0] = (_Float16)v0.x; h[1] = (_Float16)v0.y;
        h[2] = (_Float16)v0.z; h[3] = (_Float16)v0.w;
        h[4] = (_Float16)v1.x; h[5] = (_Float16)v1.y;
        h[6] = (_Float16)v1.z; h[7] = (_Float16)v1.w;
        *(half8*)(xh + i) = h;
    } else if (bid < 11264) {
        int i = (bid - 8192) * 256 + tid;       // [0, 1536*512)
        int e = i >> 9, k = i & 511;
        int proj = e >> 9, er = e & 511;
        const float* W = (proj == 0) ? Wq : ((proj == 1) ? Wk : Wv);
        Bt[i] = (_Float16)W[er * 512 + k];
    } else if (bid < 12288) {
        int i = (bid - 11264) * 256 + tid;
        WoH[i] = (_Float16)Wo[i];
    } else if (bid < 12304) {
        int p = (bid - 12288) * 256 + tid;      // 4096
        double th = -2.0 * 3.14159265358979323846 * (double)p / 4096.0;
        tw[p] = make_float2((float)cos(th), (float)sin(th));
    } else {
        int i = (bid - 12304) * 256 + tid;      // 1536
        bias[i] = (i < 512) ? bq[i] : ((i < 1024) ? bk[i - 512] : bv[i - 1024]);
    }
}

// ---------- GEMM: C = A * Bt^T (+bias), fp16, K=512, 8-phase-class schedule ----------
// (round-3 verified version: 73.2 us, FETCH 36.8 MB, 0 bank conflicts)
// 256x256 tile, BK=64 (2 k-halves of 32), 512 threads = 8 waves (2M x 4N),
// per-wave 128x64 (acc[8][4]). LDS = 2 dbuf slots x 4 sub-buffers x 16KB = 128 KB.
// Per K-tile: 4 phases {ds_read frags, stage ONE sub-buffer, bar, 16 MFMA
// (setprio), bar}; counted vmcnt(8) twice per tile; tail peels 8 -> 4 -> 0.
// k-order per accumulator: kk0 then kk1, tiles ascending -> bit-identical.
template <int MODE>
__global__ __launch_bounds__(512, 2) void gemm_f16_kernel(
    const _Float16* __restrict__ A, const _Float16* __restrict__ Bt,
    const float* __restrict__ bias,
    _Float16* __restrict__ qT, _Float16* __restrict__ kT,
    _Float16* __restrict__ vout, float* __restrict__ Cout)
{
    constexpr int NBLK   = (MODE == 0) ? 6 : 2;
    constexpr int PERXCD = (MODE == 0) ? 96 : 32;
    __shared__ _Float16 smem[65536];   // 2 x 64KB slots

    const int gi = (blockIdx.x & 7) * PERXCD + (blockIdx.x >> 3);
    const int mb = gi / NBLK;
    const int nb = gi - mb * NBLK;
    const int m0 = mb * 256, n0 = nb * 256;
    const int tid = threadIdx.x;
    const int wave = tid >> 6, lane = tid & 63;
    const int lane15 = lane & 15, quad = lane >> 4;
    const int wmr = (wave >> 2) * 128;
    const int wnr = (wave & 3) * 64;

    const int r0 = tid >> 2;                           // load0 row; load1 = +128
    const int c0 = (tid & 3) ^ ((tid >> 3) & 3);       // swizzled k-chunk (both loads)
    const char* gA = (const char*)A  + ((size_t)(m0 + r0)) * 1024 + c0 * 16;
    const char* gB = (const char*)Bt + ((size_t)(n0 + r0)) * 1024 + c0 * 16;
    const int sbw = wave * 1024;                       // wave-uniform LDS base (load0); load1 = +8192
    const int coloff = (quad ^ ((lane15 >> 1) & 3)) << 4;

    f32x4 acc[8][4];
#pragma unroll
    for (int mi = 0; mi < 8; mi++)
#pragma unroll
        for (int ni = 0; ni < 4; ni++)
#pragma unroll
            for (int r = 0; r < 4; r++) acc[mi][ni][r] = 0.f;

    auto STAGE = [&](int slot, int tensor, int kk, int kt) {
        const char* g = (tensor == 0 ? gA : gB) + kt * 128 + kk * 64;
        char* base = (char*)smem + slot * 65536 + tensor * 32768 + kk * 16384 + sbw;
        __builtin_amdgcn_global_load_lds((const AS1 void*)g, (AS3 void*)base, 16, 0, 0);
        __builtin_amdgcn_global_load_lds((const AS1 void*)(g + 131072), (AS3 void*)(base + 8192), 16, 0, 0);
    };

    half8 af[4], bf[4];
    auto LOADA = [&](int slot, int kk, int mh) {
        const char* ba = (const char*)smem + slot * 65536 + kk * 16384;
#pragma unroll
        for (int j = 0; j < 4; j++)
            af[j] = *(const half8*)(ba + (wmr + (mh * 4 + j) * 16 + lane15) * 64 + coloff);
    };
    auto LOADB = [&](int slot, int kk) {
        const char* bb = (const char*)smem + slot * 65536 + 32768 + kk * 16384;
#pragma unroll
        for (int j = 0; j < 4; j++)
            bf[j] = *(const half8*)(bb + (wnr + j * 16 + lane15) * 64 + coloff);
    };
    auto MMA = [&](int mh) {
        __builtin_amdgcn_s_setprio(1);
#pragma unroll
        for (int j = 0; j < 4; j++)
#pragma unroll
            for (int ni = 0; ni < 4; ni++)
                acc[mh * 4 + j][ni] =
                    __builtin_amdgcn_mfma_f32_16x16x32_f16(af[j], bf[ni], acc[mh * 4 + j][ni], 0, 0, 0);
        __builtin_amdgcn_s_setprio(0);
    };
#define BAR() do { __builtin_amdgcn_s_barrier(); asm volatile("" ::: "memory"); } while (0)
#define VMW(n) asm volatile("s_waitcnt vmcnt(" #n ")" ::: "memory")

    // prologue: [0].kk0 pair, [0].kk1 pair, [1].kk0 pair (12 loads); land [0].kk0.
    STAGE(0, 0, 0, 0); STAGE(0, 1, 0, 0);
    STAGE(0, 0, 1, 0); STAGE(0, 1, 1, 0);
    STAGE(1, 0, 0, 1); STAGE(1, 1, 0, 1);
    VMW(8);
    BAR();

    // K = 512 -> 8 K-tiles of 64. Steady tiles 0..5; peel 6, 7.
    for (int t = 0; t < 6; ++t) {
        const int slot = t & 1, nslot = slot ^ 1;
        // F0 (kk0, mh0)
        LOADA(slot, 0, 0); LOADB(slot, 0);
        STAGE(nslot, 0, 1, t + 1);
        BAR(); MMA(0); BAR();
        // F1 (kk0, mh1) — bf reused
        LOADA(slot, 0, 1);
        STAGE(nslot, 1, 1, t + 1);
        BAR(); MMA(1);
        VMW(8);                       // lands [t].kk1 -> guards F2 reads
        BAR();
        // F2 (kk1, mh0)
        LOADA(slot, 1, 0); LOADB(slot, 1);
        STAGE(slot, 0, 0, t + 2);
        BAR(); MMA(0); BAR();
        // F3 (kk1, mh1)
        LOADA(slot, 1, 1);
        STAGE(slot, 1, 0, t + 2);
        BAR(); MMA(1);
        VMW(8);                       // lands [t+1].kk0 -> guards next F0 reads
        BAR();
    }
    // t = 6 (slot 0): stage only [7].kk1; drain to 4
    LOADA(0, 0, 0); LOADB(0, 0); STAGE(1, 0, 1, 7); BAR(); MMA(0); BAR();
    LOADA(0, 0, 1);              STAGE(1, 1, 1, 7); BAR(); MMA(1);
    VMW(8); BAR();
    LOADA(0, 1, 0); LOADB(0, 1); BAR(); MMA(0); BAR();
    LOADA(0, 1, 1);              BAR(); MMA(1);
    VMW(4);                       // lands [7].kk0
    BAR();
    // t = 7 (slot 1): no stages; drain to 0 before kk1 reads
    LOADA(1, 0, 0); LOADB(1, 0); BAR(); MMA(0); BAR();
    LOADA(1, 0, 1);              BAR(); MMA(1);
    VMW(0);                       // lands [7].kk1
    BAR();
    LOADA(1, 1, 0); LOADB(1, 1); BAR(); MMA(0); BAR();
    LOADA(1, 1, 1);              BAR(); MMA(1);
#undef BAR
#undef VMW

    // ---- epilogue ----
    if (MODE == 1) {
#pragma unroll
        for (int mi = 0; mi < 8; mi++)
#pragma unroll
            for (int ni = 0; ni < 4; ni++) {
                const int n = n0 + wnr + ni * 16 + lane15;
                const float bb = bias[n];
#pragma unroll
                for (int r = 0; r < 4; r++) {
                    const int m = m0 + wmr + mi * 16 + quad * 4 + r;
                    Cout[(size_t)m * 512 + n] = acc[mi][ni][r] + bb;
                }
            }
        return;
    }
    const int proj = n0 >> 9;
    if (proj == 2) {   // V -> fp16 (B,H,L,D)
#pragma unroll
        for (int mi = 0; mi < 8; mi++)
#pragma unroll
            for (int ni = 0; ni < 4; ni++) {
                const int n = n0 + wnr + ni * 16 + lane15;
                const int er = n - 1024, h = er >> 6, d = er & 63;
                const float bb = bias[n];
#pragma unroll
                for (int r = 0; r < 4; r++) {
                    const int m = m0 + wmr + mi * 16 + quad * 4 + r;
                    const int b = m >> 12, l = m & 4095;
                    vout[((size_t)((b * 8 + h) * 4096 + l)) * 64 + d] = (_Float16)(acc[mi][ni][r] + bb);
                }
            }
        return;
    }
    // Q/K: packed-fp16 transposed stores. Lane holds 4 consecutive l (quad*4+r).
    _Float16* dst = (proj == 0) ? qT : kT;
    const int b = m0 >> 12;
    const int lbase = (m0 & 4095) + wmr + quad * 4;
#pragma unroll
    for (int mi = 0; mi < 8; mi++)
#pragma unroll
        for (int ni = 0; ni < 4; ni++) {
            const int e = n0 + wnr + ni * 16 + lane15;
            const int er = e & 511, h = er >> 6, d = er & 63;
            const float bb = bias[e];
            half4v o;
            o[0] = (_Float16)(acc[mi][ni][0] + bb);
            o[1] = (_Float16)(acc[mi][ni][1] + bb);
            o[2] = (_Float16)(acc[mi][ni][2] + bb);
            o[3] = (_Float16)(acc[mi][ni][3] + bb);
            *(half4v*)(dst + ((size_t)((b * 8 + h) * 64 + d)) * 4096 + lbase + mi * 16) = o;
        }
}

// ---------- FFT: 4096-pt, radix-16 (in-register DFT-16), in-place 32KB LDS ----------
__device__ __forceinline__ float2 cmul(float2 a, float2 b) {
    return make_float2(a.x * b.x - a.y * b.y, a.x * b.y + a.y * b.x);
}
__device__ __forceinline__ float2 cmulc(float2 a, float cr, float ci) {
    return make_float2(a.x * cr - a.y * ci, a.x * ci + a.y * cr);
}
__device__ __forceinline__ int swz(int i) { return i ^ ((i >> 4) & 15); }

__device__ __forceinline__ void dft16(float2 x[16]) {
    constexpr float wc[10] = {1.f, 0.92387953f, 0.70710678f, 0.38268343f, 0.f,
                              0.f, -0.70710678f, 0.f, 0.f, -0.92387953f};
    constexpr float wsn[10] = {0.f, -0.38268343f, -0.70710678f, -0.92387953f, -1.f,
                               0.f, -0.70710678f, 0.f, 0.f, 0.38268343f};
    float2 t[16];
#pragma unroll
    for (int u = 0; u < 4; u++) {
        const float2 a = x[u], b = x[u + 4], c = x[u + 8], d = x[u + 12];
        const float2 Ea = make_float2(a.x + c.x, a.y + c.y);
        const float2 Oa = make_float2(a.x - c.x, a.y - c.y);
        const float2 Eb = make_float2(b.x + d.x, b.y + d.y);
        const float2 Ob = make_float2(b.x - d.x, b.y - d.y);
        const float2 y0 = make_float2(Ea.x + Eb.x, Ea.y + Eb.y);
        const float2 y1 = make_float2(Oa.x + Ob.y, Oa.y - Ob.x);
        const float2 y2 = make_float2(Ea.x - Eb.x, Ea.y - Eb.y);
        const float2 y3 = make_float2(Oa.x - Ob.y, Oa.y + Ob.x);
        t[4 * u + 0] = y0;
        t[4 * u + 1] = cmulc(y1, wc[u * 1], wsn[u * 1]);
        t[4 * u + 2] = cmulc(y2, wc[u * 2], wsn[u * 2]);
        t[4 * u + 3] = cmulc(y3, wc[u * 3], wsn[u * 3]);
    }
#pragma unroll
    for (int v = 0; v < 4; v++) {
        const float2 a = t[v], b = t[v + 4], c = t[v + 8], d = t[v + 12];
        const float2 Ea = make_float2(a.x + c.x, a.y + c.y);
        const float2 Oa = make_float2(a.x - c.x, a.y - c.y);
        const float2 Eb = make_float2(b.x + d.x, b.y + d.y);
        const float2 Ob = make_float2(b.x - d.x, b.y - d.y);
        x[v]      = make_float2(Ea.x + Eb.x, Ea.y + Eb.y);
        x[v + 4]  = make_float2(Oa.x + Ob.y, Oa.y - Ob.x);
        x[v + 8]  = make_float2(Ea.x - Eb.x, Ea.y - Eb.y);
        x[v + 12] = make_float2(Oa.x - Ob.y, Oa.y + Ob.x);
    }
}

__device__ __forceinline__ void fft4096_r16(float2* buf, const float2* __restrict__ tw,
                                            int tid, float2 (&x)[16]) {
    __syncthreads();
#pragma unroll
    for (int j = 0; j < 16; j++) x[j] = buf[swz(tid + 256 * j)];
    __syncthreads();
    dft16(x);
    buf[swz(16 * tid)] = x[0];
#pragma unroll
    for (int m = 1; m < 16; m++) buf[swz(16 * tid + m)] = cmul(x[m], tw[tid * m]);
    __syncthreads();
#pragma unroll
    for (int j = 0; j < 16; j++) x[j] = buf[swz(tid + 256 * j)];
    __syncthreads();
    dft16(x);
    {
        const int q = tid & 15, p = tid >> 4;
        const int base = q + 256 * p;
        buf[swz(base)] = x[0];
#pragma unroll
        for (int m = 1; m < 16; m++)
            buf[swz(base + 16 * m)] = cmul(x[m], tw[(p * m) << 4]);
    }
    __syncthreads();
#pragma unroll
    for (int j = 0; j < 16; j++) x[j] = buf[swz(tid + 256 * j)];
    __syncthreads();
    dft16(x);
#pragma unroll
    for (int m = 0; m < 16; m++) buf[swz(tid + 256 * m)] = x[m];
    __syncthreads();
}

__global__ __launch_bounds__(256) void fft_partial_kernel(
    const _Float16* __restrict__ qT, const _Float16* __restrict__ kT,
    const float2* __restrict__ tw, float2* __restrict__ spec)
{
    __shared__ float2 buf[4096];
    const int tid = threadIdx.x;
    const int bh = blockIdx.x >> 4, chunk = blockIdx.x & 15;
    float sx[16], sy[16];
#pragma unroll
    for (int i = 0; i < 16; i++) { sx[i] = 0.f; sy[i] = 0.f; }
    const _Float16* qb = qT + (size_t)bh * 64 * 4096;
    const _Float16* kb = kT + (size_t)bh * 64 * 4096;
    float2 x[16];
    for (int dd = 0; dd < 4; dd++) {
        const int d = chunk * 4 + dd;
#pragma unroll
        for (int i = 0; i < 2; i++) {
            const int t0 = 2048 * i + tid * 8;
            const half8 fq = *(const half8*)(qb + d * 4096 + t0);
            const half8 fk = *(const half8*)(kb + d * 4096 + t0);
#pragma unroll
            for (int j = 0; j < 8; j++)
                buf[swz(t0 + j)] = make_float2((float)fq[j], (float)fk[j]);
        }
        fft4096_r16(buf, tw, tid, x);
        // unpack packed transforms; Zf = F[tid+256i] still in x[i].
#pragma unroll
        for (int i = 0; i < 16; i++) {
            const int f = tid + 256 * i;
            const float2 Zf = x[i];
            const float2 Zm = buf[swz((4096 - f) & 4095)];
            const float Qr  = 0.5f * (Zf.x + Zm.x);
            const float Qi  = 0.5f * (Zf.y - Zm.y);
            const float cKr = 0.5f * (Zf.y + Zm.y);
            const float cKi = 0.5f * (Zf.x - Zm.x);
            sx[i] += Qr * cKr - Qi * cKi;
            sy[i] += Qr * cKi + Qi * cKr;
        }
        __syncthreads();
    }
    float2* out = spec + (size_t)blockIdx.x * 4096;
#pragma unroll
    for (int i = 0; i < 16; i++) out[tid + 256 * i] = make_float2(sx[i], sy[i]);
}

// ---------- sum of 16 partial spectra (+conj), vectorized float4 ----------
__global__ __launch_bounds__(256) void sum_spec_kernel(
    const float4* __restrict__ spec4, float4* __restrict__ ssum4)
{
    const int bh = blockIdx.x >> 3;
    const int i4 = (blockIdx.x & 7) * 256 + threadIdx.x;
    const float4* base = spec4 + (size_t)bh * 16 * 2048 + i4;
    float4 s = make_float4(0.f, 0.f, 0.f, 0.f);
#pragma unroll
    for (int c = 0; c < 16; c++) {
        const float4 v = base[(size_t)c * 2048];
        s.x += v.x; s.y += v.y; s.z += v.z; s.w += v.w;
    }
    s.y = -s.y; s.w = -s.w;   // conj
    ssum4[(size_t)bh * 2048 + i4] = s;
}

// per block: one (b,h). corr = Re(FFT(conj(S))); top-8 + softmax.
// Wave-parallel top-8 (register-resident), tid0 merges 4x8 candidates with the
// identical (val desc, idx asc) comparator -> selection bitwise-identical.
__global__ __launch_bounds__(256) void reduce_topk_kernel(
    const float2* __restrict__ ssum, const float2* __restrict__ tw,
    int* __restrict__ top_idx, float* __restrict__ top_w)
{
    __shared__ float2 buf[4096];
    __shared__ float cval[32];
    __shared__ int cidx[32];
    const int tid = threadIdx.x;
    const int bh = blockIdx.x;
#pragma unroll
    for (int i = 0; i < 16; i++) {
        const int f = tid + 256 * i;
        buf[swz(f)] = ssum[(size_t)bh * 4096 + f];
    }
    float2 x[16];
    fft4096_r16(buf, tw, tid, x);
    const int wid = tid >> 6;
    float c[16];
#pragma unroll
    for (int i = 0; i < 16; i++) c[i] = buf[swz(tid + 256 * i)].x;
    for (int k = 0; k < 8; k++) {
        float best = -3.0e38f; int bi = 0;
#pragma unroll
        for (int i = 0; i < 16; i++) {
            const int f = tid + 256 * i;
            if (c[i] > best) { best = c[i]; bi = f; }
        }
#pragma unroll
        for (int off = 32; off > 0; off >>= 1) {
            const float ov = __shfl_down(best, off);
            const int oi = __shfl_down(bi, off);
            if (ov > best || (ov == best && oi < bi)) { best = ov; bi = oi; }
        }
        best = __shfl(best, 0); bi = __shfl(bi, 0);
        if ((tid & 63) == 0) { cval[wid * 8 + k] = best; cidx[wid * 8 + k] = bi; }
        // invalidate winner in its owner thread's registers (static indexing)
        const int ii = bi >> 8;
#pragma unroll
        for (int i = 0; i < 16; i++)
            if (i == ii && tid == (bi & 255)) c[i] = -3.4e38f;
    }
    __syncthreads();
    if (tid == 0) {
        float vals[8]; int idxs[8];
        for (int k = 0; k < 8; k++) {
            float best = -3.0e38f; int bi = 0; int bc = 0;
            for (int cc = 0; cc < 32; cc++) {
                const float v = cval[cc]; const int ix = cidx[cc];
                if (v > best || (v == best && ix < bi)) { best = v; bi = ix; bc = cc; }
            }
            cval[bc] = -3.4e38f;
            vals[k] = best; idxs[k] = bi;
        }
        const float scale = 1.f / (4096.f * 64.f);
        float e[8], s = 0.f;
        const float mx = vals[0] * scale;
        for (int k = 0; k < 8; k++) { e[k] = __expf(vals[k] * scale - mx); s += e[k]; }
        for (int k = 0; k < 8; k++) {
            top_w[bh * 8 + k] = e[k] / s;
            top_idx[bh * 8 + k] = idxs[k];
        }
    }
}

// ---------- gather: out_pre[b,l,h*64+d] = sum_k w_k * v[b,h,(l+idx_k)%L,d] ----------
// Grid-stride 4 seq/block; bh constant within block (128 % 4 == 0) so idx/w
// load once. 16 B/lane half8 loads; k-ascending accumulation -> bit-identical.
__global__ __launch_bounds__(256) void gather_kernel(
    const half8* __restrict__ v8, const int* __restrict__ top_idx,
    const float* __restrict__ top_w, half8* __restrict__ out8)
{
    const int bh = blockIdx.x >> 5;       // 2048 blocks; 4 seq each, same bh
    const int b = bh >> 3, h = bh & 7;
    const int tid = threadIdx.x;
    const int d8 = tid & 7;
    int idx[8]; float w[8];
#pragma unroll
    for (int k = 0; k < 8; k++) { idx[k] = top_idx[bh * 8 + k]; w[k] = top_w[bh * 8 + k]; }
    const half8* vb = v8 + (size_t)bh * 4096 * 8;
#pragma unroll
    for (int it = 0; it < 4; ++it) {
        const int seq = blockIdx.x * 4 + it;
        const int lgrp = seq & 127;
        const int l = lgrp * 32 + (tid >> 3);
        float a[8];
#pragma unroll
        for (int j = 0; j < 8; j++) a[j] = 0.f;
#pragma unroll
        for (int k = 0; k < 8; k++) {
            const int ls = (l + idx[k]) & 4095;
            const half8 pv = vb[(size_t)ls * 8 + d8];
#pragma unroll
            for (int j = 0; j < 8; j++) a[j] += w[k] * (float)pv[j];
        }
        half8 o;
#pragma unroll
        for (int j = 0; j < 8; j++) o[j] = (_Float16)a[j];
        out8[((size_t)(b * 4096 + l)) * 64 + h * 8 + d8] = o;
    }
}

// ---------- host ----------
extern "C" void kernel_launch(void* const* d_in, const int* in_sizes, int n_in,
                              void* d_out, int out_size, void* d_ws, size_t ws_size,
                              hipStream_t stream) {
    (void)in_sizes; (void)n_in; (void)out_size; (void)ws_size;
    const float* x  = (const float*)d_in[0];
    const float* Wq = (const float*)d_in[1];
    const float* bq = (const float*)d_in[2];
    const float* Wk = (const float*)d_in[3];
    const float* bk = (const float*)d_in[4];
    const float* Wv = (const float*)d_in[5];
    const float* bv = (const float*)d_in[6];
    const float* Wo = (const float*)d_in[7];
    const float* bo = (const float*)d_in[8];
    float* out = (float*)d_out;

    char* ws = (char*)d_ws;
    size_t off = 0;
    auto alloc = [&](size_t bytes) -> void* {
        void* p = ws + off; off += (bytes + 255) & ~(size_t)255; return p;
    };
    _Float16* xh   = (_Float16*)alloc(33554432);   // 32768x512 fp16
    _Float16* qT   = (_Float16*)alloc(33554432);   // (B,H,D,L) fp16
    _Float16* kT   = (_Float16*)alloc(33554432);
    _Float16* vbuf = (_Float16*)alloc(33554432);   // (B,H,L,D) fp16
    float2* spec   = (float2*)alloc(33554432);     // 1024 x 4096 float2
    float2* ssum   = (float2*)alloc(2097152);      // 64 x 4096 float2 (summed, conj)
    _Float16* BtH  = (_Float16*)alloc(1572864);    // 1536x512 fp16
    _Float16* WoH  = (_Float16*)alloc(524288);     // 512x512 fp16
    float* biasQKV = (float*)alloc(6144);          // 1536 fp32
    float2* tw     = (float2*)alloc(32768);        // 4096 twiddles
    int*   top_idx = (int*)alloc(2048);
    float* top_w   = (float*)alloc(2048);
    _Float16* out_pre = xh;                        // alias: xh dead after GEMM1

    prep_all_kernel<<<12310, 256, 0, stream>>>(x, Wq, Wk, Wv, Wo, bq, bk, bv,
                                               xh, BtH, WoH, tw, biasQKV);
    gemm_f16_kernel<0><<<768, 512, 0, stream>>>(xh, BtH, biasQKV, qT, kT, vbuf, nullptr);
    fft_partial_kernel<<<1024, 256, 0, stream>>>(qT, kT, tw, spec);
    sum_spec_kernel<<<512, 256, 0, stream>>>((const float4*)spec, (float4*)ssum);
    reduce_topk_kernel<<<64, 256, 0, stream>>>(ssum, tw, top_idx, top_w);
    gather_kernel<<<2048, 256, 0, stream>>>((const half8*)vbuf, top_idx, top_w,
                                            (half8*)out_pre);
    gemm_f16_kernel<1><<<256, 512, 0, stream>>>(out_pre, WoH, bo, nullptr, nullptr, nullptr, out);
}

// Round 7
// 337.987 us; speedup vs baseline: 1.0389x; 1.0389x over previous
//
#include <hip/hip_runtime.h>
#include <cstdint>
#include <cstddef>

#define AS1 __attribute__((address_space(1)))
#define AS3 __attribute__((address_space(3)))

using half8  = __attribute__((ext_vector_type(8))) _Float16;
using half4v = __attribute__((ext_vector_type(4))) _Float16;
using half2v = __attribute__((ext_vector_type(2))) _Float16;
using f32x4  = __attribute__((ext_vector_type(4))) float;

// ---------- fused prep kernel ----------
// [0,16384):        x -> fp16 (16.8M elems, 4/thread)  [R0-verified form]
// [16384,19456):    Bt 1536x512 fp16 (rows: q|k|v projection weights)
// [19456,20480):    Wo -> fp16 512x512
// [20480,20496):    twiddles (4096: W_4096^p)
// [20496,20502):    bias concat (1536)
__global__ void prep_all_kernel(const float* __restrict__ x,
                                const float* __restrict__ Wq, const float* __restrict__ Wk,
                                const float* __restrict__ Wv, const float* __restrict__ Wo,
                                const float* __restrict__ bq, const float* __restrict__ bk,
                                const float* __restrict__ bv,
                                _Float16* __restrict__ xh, _Float16* __restrict__ Bt,
                                _Float16* __restrict__ WoH,
                                float2* __restrict__ tw, float* __restrict__ bias) {
    const int bid = blockIdx.x;
    const int tid = threadIdx.x;
    if (bid < 16384) {
        int i = (bid * 256 + tid) * 4;
        float4 v = *(const float4*)(x + i);
        half4v h;
        h[0] = (_Float16)v.x; h[1] = (_Float16)v.y;
        h[2] = (_Float16)v.z; h[3] = (_Float16)v.w;
        *(half4v*)(xh + i) = h;
    } else if (bid < 19456) {
        int i = (bid - 16384) * 256 + tid;      // [0, 1536*512)
        int e = i >> 9, k = i & 511;
        int proj = e >> 9, er = e & 511;
        const float* W = (proj == 0) ? Wq : ((proj == 1) ? Wk : Wv);
        Bt[i] = (_Float16)W[er * 512 + k];
    } else if (bid < 20480) {
        int i = (bid - 19456) * 256 + tid;
        WoH[i] = (_Float16)Wo[i];
    } else if (bid < 20496) {
        int p = (bid - 20480) * 256 + tid;      // 4096
        double th = -2.0 * 3.14159265358979323846 * (double)p / 4096.0;
        tw[p] = make_float2((float)cos(th), (float)sin(th));
    } else {
        int i = (bid - 20496) * 256 + tid;      // 1536
        bias[i] = (i < 512) ? bq[i] : ((i < 1024) ? bk[i - 512] : bv[i - 1024]);
    }
}

// ---------- GEMM: C = A * Bt^T (+bias), fp16, K=512, 8-phase-class schedule ----------
// (round-3 verified, re-verified round 6: 71.7-73.2 us, FETCH 37 MB, 0 conflicts)
// 256x256 tile, BK=64 (2 k-halves of 32), 512 threads = 8 waves (2M x 4N),
// per-wave 128x64 (acc[8][4]). LDS = 2 dbuf slots x 4 sub-buffers x 16KB = 128 KB.
// Per K-tile: 4 phases {ds_read frags, stage ONE sub-buffer, bar, 16 MFMA
// (setprio), bar}; counted vmcnt(8) twice per tile; tail peels 8 -> 4 -> 0.
// k-order per accumulator: kk0 then kk1, tiles ascending -> bit-identical.
template <int MODE>
__global__ __launch_bounds__(512, 2) void gemm_f16_kernel(
    const _Float16* __restrict__ A, const _Float16* __restrict__ Bt,
    const float* __restrict__ bias,
    _Float16* __restrict__ qT, _Float16* __restrict__ kT,
    _Float16* __restrict__ vout, float* __restrict__ Cout)
{
    constexpr int NBLK   = (MODE == 0) ? 6 : 2;
    constexpr int PERXCD = (MODE == 0) ? 96 : 32;
    __shared__ _Float16 smem[65536];   // 2 x 64KB slots

    const int gi = (blockIdx.x & 7) * PERXCD + (blockIdx.x >> 3);
    const int mb = gi / NBLK;
    const int nb = gi - mb * NBLK;
    const int m0 = mb * 256, n0 = nb * 256;
    const int tid = threadIdx.x;
    const int wave = tid >> 6, lane = tid & 63;
    const int lane15 = lane & 15, quad = lane >> 4;
    const int wmr = (wave >> 2) * 128;
    const int wnr = (wave & 3) * 64;

    const int r0 = tid >> 2;                           // load0 row; load1 = +128
    const int c0 = (tid & 3) ^ ((tid >> 3) & 3);       // swizzled k-chunk (both loads)
    const char* gA = (const char*)A  + ((size_t)(m0 + r0)) * 1024 + c0 * 16;
    const char* gB = (const char*)Bt + ((size_t)(n0 + r0)) * 1024 + c0 * 16;
    const int sbw = wave * 1024;                       // wave-uniform LDS base (load0); load1 = +8192
    const int coloff = (quad ^ ((lane15 >> 1) & 3)) << 4;

    f32x4 acc[8][4];
#pragma unroll
    for (int mi = 0; mi < 8; mi++)
#pragma unroll
        for (int ni = 0; ni < 4; ni++)
#pragma unroll
            for (int r = 0; r < 4; r++) acc[mi][ni][r] = 0.f;

    auto STAGE = [&](int slot, int tensor, int kk, int kt) {
        const char* g = (tensor == 0 ? gA : gB) + kt * 128 + kk * 64;
        char* base = (char*)smem + slot * 65536 + tensor * 32768 + kk * 16384 + sbw;
        __builtin_amdgcn_global_load_lds((const AS1 void*)g, (AS3 void*)base, 16, 0, 0);
        __builtin_amdgcn_global_load_lds((const AS1 void*)(g + 131072), (AS3 void*)(base + 8192), 16, 0, 0);
    };

    half8 af[4], bf[4];
    auto LOADA = [&](int slot, int kk, int mh) {
        const char* ba = (const char*)smem + slot * 65536 + kk * 16384;
#pragma unroll
        for (int j = 0; j < 4; j++)
            af[j] = *(const half8*)(ba + (wmr + (mh * 4 + j) * 16 + lane15) * 64 + coloff);
    };
    auto LOADB = [&](int slot, int kk) {
        const char* bb = (const char*)smem + slot * 65536 + 32768 + kk * 16384;
#pragma unroll
        for (int j = 0; j < 4; j++)
            bf[j] = *(const half8*)(bb + (wnr + j * 16 + lane15) * 64 + coloff);
    };
    auto MMA = [&](int mh) {
        __builtin_amdgcn_s_setprio(1);
#pragma unroll
        for (int j = 0; j < 4; j++)
#pragma unroll
            for (int ni = 0; ni < 4; ni++)
                acc[mh * 4 + j][ni] =
                    __builtin_amdgcn_mfma_f32_16x16x32_f16(af[j], bf[ni], acc[mh * 4 + j][ni], 0, 0, 0);
        __builtin_amdgcn_s_setprio(0);
    };
#define BAR() do { __builtin_amdgcn_s_barrier(); asm volatile("" ::: "memory"); } while (0)
#define VMW(n) asm volatile("s_waitcnt vmcnt(" #n ")" ::: "memory")

    // prologue: [0].kk0 pair, [0].kk1 pair, [1].kk0 pair (12 loads); land [0].kk0.
    STAGE(0, 0, 0, 0); STAGE(0, 1, 0, 0);
    STAGE(0, 0, 1, 0); STAGE(0, 1, 1, 0);
    STAGE(1, 0, 0, 1); STAGE(1, 1, 0, 1);
    VMW(8);
    BAR();

    // K = 512 -> 8 K-tiles of 64. Steady tiles 0..5; peel 6, 7.
    for (int t = 0; t < 6; ++t) {
        const int slot = t & 1, nslot = slot ^ 1;
        // F0 (kk0, mh0)
        LOADA(slot, 0, 0); LOADB(slot, 0);
        STAGE(nslot, 0, 1, t + 1);
        BAR(); MMA(0); BAR();
        // F1 (kk0, mh1) — bf reused
        LOADA(slot, 0, 1);
        STAGE(nslot, 1, 1, t + 1);
        BAR(); MMA(1);
        VMW(8);                       // lands [t].kk1 -> guards F2 reads
        BAR();
        // F2 (kk1, mh0)
        LOADA(slot, 1, 0); LOADB(slot, 1);
        STAGE(slot, 0, 0, t + 2);
        BAR(); MMA(0); BAR();
        // F3 (kk1, mh1)
        LOADA(slot, 1, 1);
        STAGE(slot, 1, 0, t + 2);
        BAR(); MMA(1);
        VMW(8);                       // lands [t+1].kk0 -> guards next F0 reads
        BAR();
    }
    // t = 6 (slot 0): stage only [7].kk1; drain to 4
    LOADA(0, 0, 0); LOADB(0, 0); STAGE(1, 0, 1, 7); BAR(); MMA(0); BAR();
    LOADA(0, 0, 1);              STAGE(1, 1, 1, 7); BAR(); MMA(1);
    VMW(8); BAR();
    LOADA(0, 1, 0); LOADB(0, 1); BAR(); MMA(0); BAR();
    LOADA(0, 1, 1);              BAR(); MMA(1);
    VMW(4);                       // lands [7].kk0
    BAR();
    // t = 7 (slot 1): no stages; drain to 0 before kk1 reads
    LOADA(1, 0, 0); LOADB(1, 0); BAR(); MMA(0); BAR();
    LOADA(1, 0, 1);              BAR(); MMA(1);
    VMW(0);                       // lands [7].kk1
    BAR();
    LOADA(1, 1, 0); LOADB(1, 1); BAR(); MMA(0); BAR();
    LOADA(1, 1, 1);              BAR(); MMA(1);
#undef BAR
#undef VMW

    // ---- epilogue ----
    if (MODE == 1) {
#pragma unroll
        for (int mi = 0; mi < 8; mi++)
#pragma unroll
            for (int ni = 0; ni < 4; ni++) {
                const int n = n0 + wnr + ni * 16 + lane15;
                const float bb = bias[n];
#pragma unroll
                for (int r = 0; r < 4; r++) {
                    const int m = m0 + wmr + mi * 16 + quad * 4 + r;
                    Cout[(size_t)m * 512 + n] = acc[mi][ni][r] + bb;
                }
            }
        return;
    }
    const int proj = n0 >> 9;
    if (proj == 2) {   // V -> fp16 (B,H,L,D)
#pragma unroll
        for (int mi = 0; mi < 8; mi++)
#pragma unroll
            for (int ni = 0; ni < 4; ni++) {
                const int n = n0 + wnr + ni * 16 + lane15;
                const int er = n - 1024, h = er >> 6, d = er & 63;
                const float bb = bias[n];
#pragma unroll
                for (int r = 0; r < 4; r++) {
                    const int m = m0 + wmr + mi * 16 + quad * 4 + r;
                    const int b = m >> 12, l = m & 4095;
                    vout[((size_t)((b * 8 + h) * 4096 + l)) * 64 + d] = (_Float16)(acc[mi][ni][r] + bb);
                }
            }
        return;
    }
    // Q/K: packed-fp16 transposed stores. Lane holds 4 consecutive l (quad*4+r).
    _Float16* dst = (proj == 0) ? qT : kT;
    const int b = m0 >> 12;
    const int lbase = (m0 & 4095) + wmr + quad * 4;
#pragma unroll
    for (int mi = 0; mi < 8; mi++)
#pragma unroll
        for (int ni = 0; ni < 4; ni++) {
            const int e = n0 + wnr + ni * 16 + lane15;
            const int er = e & 511, h = er >> 6, d = er & 63;
            const float bb = bias[e];
            half4v o;
            o[0] = (_Float16)(acc[mi][ni][0] + bb);
            o[1] = (_Float16)(acc[mi][ni][1] + bb);
            o[2] = (_Float16)(acc[mi][ni][2] + bb);
            o[3] = (_Float16)(acc[mi][ni][3] + bb);
            *(half4v*)(dst + ((size_t)((b * 8 + h) * 64 + d)) * 4096 + lbase + mi * 16) = o;
        }
}

// ---------- FFT: 4096-pt, radix-16 (in-register DFT-16), in-place 32KB LDS ----------
__device__ __forceinline__ float2 cmul(float2 a, float2 b) {
    return make_float2(a.x * b.x - a.y * b.y, a.x * b.y + a.y * b.x);
}
__device__ __forceinline__ float2 cmulc(float2 a, float cr, float ci) {
    return make_float2(a.x * cr - a.y * ci, a.x * ci + a.y * cr);
}
__device__ __forceinline__ int swz(int i) { return i ^ ((i >> 4) & 15); }

__device__ __forceinline__ void dft16(float2 x[16]) {
    constexpr float wc[10] = {1.f, 0.92387953f, 0.70710678f, 0.38268343f, 0.f,
                              0.f, -0.70710678f, 0.f, 0.f, -0.92387953f};
    constexpr float wsn[10] = {0.f, -0.38268343f, -0.70710678f, -0.92387953f, -1.f,
                               0.f, -0.70710678f, 0.f, 0.f, 0.38268343f};
    float2 t[16];
#pragma unroll
    for (int u = 0; u < 4; u++) {
        const float2 a = x[u], b = x[u + 4], c = x[u + 8], d = x[u + 12];
        const float2 Ea = make_float2(a.x + c.x, a.y + c.y);
        const float2 Oa = make_float2(a.x - c.x, a.y - c.y);
        const float2 Eb = make_float2(b.x + d.x, b.y + d.y);
        const float2 Ob = make_float2(b.x - d.x, b.y - d.y);
        const float2 y0 = make_float2(Ea.x + Eb.x, Ea.y + Eb.y);
        const float2 y1 = make_float2(Oa.x + Ob.y, Oa.y - Ob.x);
        const float2 y2 = make_float2(Ea.x - Eb.x, Ea.y - Eb.y);
        const float2 y3 = make_float2(Oa.x - Ob.y, Oa.y + Ob.x);
        t[4 * u + 0] = y0;
        t[4 * u + 1] = cmulc(y1, wc[u * 1], wsn[u * 1]);
        t[4 * u + 2] = cmulc(y2, wc[u * 2], wsn[u * 2]);
        t[4 * u + 3] = cmulc(y3, wc[u * 3], wsn[u * 3]);
    }
#pragma unroll
    for (int v = 0; v < 4; v++) {
        const float2 a = t[v], b = t[v + 4], c = t[v + 8], d = t[v + 12];
        const float2 Ea = make_float2(a.x + c.x, a.y + c.y);
        const float2 Oa = make_float2(a.x - c.x, a.y - c.y);
        const float2 Eb = make_float2(b.x + d.x, b.y + d.y);
        const float2 Ob = make_float2(b.x - d.x, b.y - d.y);
        x[v]      = make_float2(Ea.x + Eb.x, Ea.y + Eb.y);
        x[v + 4]  = make_float2(Oa.x + Ob.y, Oa.y - Ob.x);
        x[v + 8]  = make_float2(Ea.x - Eb.x, Ea.y - Eb.y);
        x[v + 12] = make_float2(Oa.x - Ob.y, Oa.y + Ob.x);
    }
}

__device__ __forceinline__ void fft4096_r16(float2* buf, const float2* __restrict__ tw,
                                            int tid, float2 (&x)[16]) {
    __syncthreads();
#pragma unroll
    for (int j = 0; j < 16; j++) x[j] = buf[swz(tid + 256 * j)];
    __syncthreads();
    dft16(x);
    buf[swz(16 * tid)] = x[0];
#pragma unroll
    for (int m = 1; m < 16; m++) buf[swz(16 * tid + m)] = cmul(x[m], tw[tid * m]);
    __syncthreads();
#pragma unroll
    for (int j = 0; j < 16; j++) x[j] = buf[swz(tid + 256 * j)];
    __syncthreads();
    dft16(x);
    {
        const int q = tid & 15, p = tid >> 4;
        const int base = q + 256 * p;
        buf[swz(base)] = x[0];
#pragma unroll
        for (int m = 1; m < 16; m++)
            buf[swz(base + 16 * m)] = cmul(x[m], tw[(p * m) << 4]);
    }
    __syncthreads();
#pragma unroll
    for (int j = 0; j < 16; j++) x[j] = buf[swz(tid + 256 * j)];
    __syncthreads();
    dft16(x);
#pragma unroll
    for (int m = 0; m < 16; m++) buf[swz(tid + 256 * m)] = x[m];
    __syncthreads();
}

__global__ __launch_bounds__(256) void fft_partial_kernel(
    const _Float16* __restrict__ qT, const _Float16* __restrict__ kT,
    const float2* __restrict__ tw, float2* __restrict__ spec)
{
    __shared__ float2 buf[4096];
    const int tid = threadIdx.x;
    const int bh = blockIdx.x >> 4, chunk = blockIdx.x & 15;
    float sx[16], sy[16];
#pragma unroll
    for (int i = 0; i < 16; i++) { sx[i] = 0.f; sy[i] = 0.f; }
    const _Float16* qb = qT + (size_t)bh * 64 * 4096;
    const _Float16* kb = kT + (size_t)bh * 64 * 4096;
    float2 x[16];
    for (int dd = 0; dd < 4; dd++) {
        const int d = chunk * 4 + dd;
#pragma unroll
        for (int i = 0; i < 2; i++) {
            const int t0 = 2048 * i + tid * 8;
            const half8 fq = *(const half8*)(qb + d * 4096 + t0);
            const half8 fk = *(const half8*)(kb + d * 4096 + t0);
#pragma unroll
            for (int j = 0; j < 8; j++)
                buf[swz(t0 + j)] = make_float2((float)fq[j], (float)fk[j]);
        }
        fft4096_r16(buf, tw, tid, x);
        // unpack packed transforms; Zf = F[tid+256i] still in x[i].
#pragma unroll
        for (int i = 0; i < 16; i++) {
            const int f = tid + 256 * i;
            const float2 Zf = x[i];
            const float2 Zm = buf[swz((4096 - f) & 4095)];
            const float Qr  = 0.5f * (Zf.x + Zm.x);
            const float Qi  = 0.5f * (Zf.y - Zm.y);
            const float cKr = 0.5f * (Zf.y + Zm.y);
            const float cKi = 0.5f * (Zf.x - Zm.x);
            sx[i] += Qr * cKr - Qi * cKi;
            sy[i] += Qr * cKi + Qi * cKr;
        }
        __syncthreads();
    }
    float2* out = spec + (size_t)blockIdx.x * 4096;
#pragma unroll
    for (int i = 0; i < 16; i++) out[tid + 256 * i] = make_float2(sx[i], sy[i]);
}

// ---------- sum of 16 partial spectra (+conj), vectorized float4 ----------
__global__ __launch_bounds__(256) void sum_spec_kernel(
    const float4* __restrict__ spec4, float4* __restrict__ ssum4)
{
    const int bh = blockIdx.x >> 3;
    const int i4 = (blockIdx.x & 7) * 256 + threadIdx.x;
    const float4* base = spec4 + (size_t)bh * 16 * 2048 + i4;
    float4 s = make_float4(0.f, 0.f, 0.f, 0.f);
#pragma unroll
    for (int c = 0; c < 16; c++) {
        const float4 v = base[(size_t)c * 2048];
        s.x += v.x; s.y += v.y; s.z += v.z; s.w += v.w;
    }
    s.y = -s.y; s.w = -s.w;   // conj
    ssum4[(size_t)bh * 2048 + i4] = s;
}

// per block: one (b,h). corr = Re(FFT(conj(S))); top-8 + softmax.
// Wave-parallel top-8 (register-resident), tid0 merges 4x8 candidates with the
// identical (val desc, idx asc) comparator -> selection bitwise-identical.
__global__ __launch_bounds__(256) void reduce_topk_kernel(
    const float2* __restrict__ ssum, const float2* __restrict__ tw,
    int* __restrict__ top_idx, float* __restrict__ top_w)
{
    __shared__ float2 buf[4096];
    __shared__ float cval[32];
    __shared__ int cidx[32];
    const int tid = threadIdx.x;
    const int bh = blockIdx.x;
#pragma unroll
    for (int i = 0; i < 16; i++) {
        const int f = tid + 256 * i;
        buf[swz(f)] = ssum[(size_t)bh * 4096 + f];
    }
    float2 x[16];
    fft4096_r16(buf, tw, tid, x);
    const int wid = tid >> 6;
    float c[16];
#pragma unroll
    for (int i = 0; i < 16; i++) c[i] = buf[swz(tid + 256 * i)].x;
    for (int k = 0; k < 8; k++) {
        float best = -3.0e38f; int bi = 0;
#pragma unroll
        for (int i = 0; i < 16; i++) {
            const int f = tid + 256 * i;
            if (c[i] > best) { best = c[i]; bi = f; }
        }
#pragma unroll
        for (int off = 32; off > 0; off >>= 1) {
            const float ov = __shfl_down(best, off);
            const int oi = __shfl_down(bi, off);
            if (ov > best || (ov == best && oi < bi)) { best = ov; bi = oi; }
        }
        best = __shfl(best, 0); bi = __shfl(bi, 0);
        if ((tid & 63) == 0) { cval[wid * 8 + k] = best; cidx[wid * 8 + k] = bi; }
        // invalidate winner in its owner thread's registers (static indexing)
        const int ii = bi >> 8;
#pragma unroll
        for (int i = 0; i < 16; i++)
            if (i == ii && tid == (bi & 255)) c[i] = -3.4e38f;
    }
    __syncthreads();
    if (tid == 0) {
        float vals[8]; int idxs[8];
        for (int k = 0; k < 8; k++) {
            float best = -3.0e38f; int bi = 0; int bc = 0;
            for (int cc = 0; cc < 32; cc++) {
                const float v = cval[cc]; const int ix = cidx[cc];
                if (v > best || (v == best && ix < bi)) { best = v; bi = ix; bc = cc; }
            }
            cval[bc] = -3.4e38f;
            vals[k] = best; idxs[k] = bi;
        }
        const float scale = 1.f / (4096.f * 64.f);
        float e[8], s = 0.f;
        const float mx = vals[0] * scale;
        for (int k = 0; k < 8; k++) { e[k] = __expf(vals[k] * scale - mx); s += e[k]; }
        for (int k = 0; k < 8; k++) {
            top_w[bh * 8 + k] = e[k] / s;
            top_idx[bh * 8 + k] = idxs[k];
        }
    }
}

// ---------- gather: out_pre[b,l,h*64+d] = sum_k w_k * v[b,h,(l+idx_k)%L,d] ----------
// R4-verified form: 8192 blocks, 16 B/lane half8 loads, natural block order.
// k-ascending accumulation -> bit-identical.
__global__ __launch_bounds__(256) void gather_kernel(
    const half8* __restrict__ v8, const int* __restrict__ top_idx,
    const float* __restrict__ top_w, half8* __restrict__ out8)
{
    const int seq = blockIdx.x;           // 8192 = 64 bh * 128 lgrp
    const int bh = seq >> 7;
    const int lgrp = seq & 127;
    const int b = bh >> 3, h = bh & 7;
    const int tid = threadIdx.x;
    const int l = lgrp * 32 + (tid >> 3);
    const int d8 = tid & 7;
    int idx[8]; float w[8];
#pragma unroll
    for (int k = 0; k < 8; k++) { idx[k] = top_idx[bh * 8 + k]; w[k] = top_w[bh * 8 + k]; }
    const half8* vb = v8 + (size_t)bh * 4096 * 8;
    float a[8];
#pragma unroll
    for (int j = 0; j < 8; j++) a[j] = 0.f;
#pragma unroll
    for (int k = 0; k < 8; k++) {
        const int ls = (l + idx[k]) & 4095;
        const half8 pv = vb[(size_t)ls * 8 + d8];
#pragma unroll
        for (int j = 0; j < 8; j++) a[j] += w[k] * (float)pv[j];
    }
    half8 o;
#pragma unroll
    for (int j = 0; j < 8; j++) o[j] = (_Float16)a[j];
    out8[((size_t)(b * 4096 + l)) * 64 + h * 8 + d8] = o;
}

// ---------- host ----------
extern "C" void kernel_launch(void* const* d_in, const int* in_sizes, int n_in,
                              void* d_out, int out_size, void* d_ws, size_t ws_size,
                              hipStream_t stream) {
    (void)in_sizes; (void)n_in; (void)out_size; (void)ws_size;
    const float* x  = (const float*)d_in[0];
    const float* Wq = (const float*)d_in[1];
    const float* bq = (const float*)d_in[2];
    const float* Wk = (const float*)d_in[3];
    const float* bk = (const float*)d_in[4];
    const float* Wv = (const float*)d_in[5];
    const float* bv = (const float*)d_in[6];
    const float* Wo = (const float*)d_in[7];
    const float* bo = (const float*)d_in[8];
    float* out = (float*)d_out;

    char* ws = (char*)d_ws;
    size_t off = 0;
    auto alloc = [&](size_t bytes) -> void* {
        void* p = ws + off; off += (bytes + 255) & ~(size_t)255; return p;
    };
    _Float16* xh   = (_Float16*)alloc(33554432);   // 32768x512 fp16
    _Float16* qT   = (_Float16*)alloc(33554432);   // (B,H,D,L) fp16
    _Float16* kT   = (_Float16*)alloc(33554432);
    _Float16* vbuf = (_Float16*)alloc(33554432);   // (B,H,L,D) fp16
    float2* spec   = (float2*)alloc(33554432);     // 1024 x 4096 float2
    float2* ssum   = (float2*)alloc(2097152);      // 64 x 4096 float2 (summed, conj)
    _Float16* BtH  = (_Float16*)alloc(1572864);    // 1536x512 fp16
    _Float16* WoH  = (_Float16*)alloc(524288);     // 512x512 fp16
    float* biasQKV = (float*)alloc(6144);          // 1536 fp32
    float2* tw     = (float2*)alloc(32768);        // 4096 twiddles
    int*   top_idx = (int*)alloc(2048);
    float* top_w   = (float*)alloc(2048);
    _Float16* out_pre = xh;                        // alias: xh dead after GEMM1

    prep_all_kernel<<<20502, 256, 0, stream>>>(x, Wq, Wk, Wv, Wo, bq, bk, bv,
                                               xh, BtH, WoH, tw, biasQKV);
    gemm_f16_kernel<0><<<768, 512, 0, stream>>>(xh, BtH, biasQKV, qT, kT, vbuf, nullptr);
    fft_partial_kernel<<<1024, 256, 0, stream>>>(qT, kT, tw, spec);
    sum_spec_kernel<<<512, 256, 0, stream>>>((const float4*)spec, (float4*)ssum);
    reduce_topk_kernel<<<64, 256, 0, stream>>>(ssum, tw, top_idx, top_w);
    gather_kernel<<<8192, 256, 0, stream>>>((const half8*)vbuf, top_idx, top_w,
                                            (half8*)out_pre);
    gemm_f16_kernel<1><<<256, 512, 0, stream>>>(out_pre, WoH, bo, nullptr, nullptr, nullptr, out);
}

// Round 9
// 301.841 us; speedup vs baseline: 1.1633x; 1.1198x over previous
//
#include <hip/hip_runtime.h>
#include <cstdint>
#include <cstddef>

#define AS1 __attribute__((address_space(1)))
#define AS3 __attribute__((address_space(3)))

using half8  = __attribute__((ext_vector_type(8))) _Float16;
using half4v = __attribute__((ext_vector_type(4))) _Float16;
using half2v = __attribute__((ext_vector_type(2))) _Float16;
using f32x4  = __attribute__((ext_vector_type(4))) float;

// ---------- fused prep kernel ----------
__global__ void prep_all_kernel(const float* __restrict__ x,
                                const float* __restrict__ Wq, const float* __restrict__ Wk,
                                const float* __restrict__ Wv, const float* __restrict__ Wo,
                                const float* __restrict__ bq, const float* __restrict__ bk,
                                const float* __restrict__ bv,
                                _Float16* __restrict__ xh, _Float16* __restrict__ Bt,
                                _Float16* __restrict__ WoH,
                                float2* __restrict__ tw, float* __restrict__ bias) {
    const int bid = blockIdx.x;
    const int tid = threadIdx.x;
    if (bid < 16384) {
        int i = (bid * 256 + tid) * 4;
        float4 v = *(const float4*)(x + i);
        half4v h;
        h[0] = (_Float16)v.x; h[1] = (_Float16)v.y;
        h[2] = (_Float16)v.z; h[3] = (_Float16)v.w;
        *(half4v*)(xh + i) = h;
    } else if (bid < 19456) {
        int i = (bid - 16384) * 256 + tid;      // [0, 1536*512)
        int e = i >> 9, k = i & 511;
        int proj = e >> 9, er = e & 511;
        const float* W = (proj == 0) ? Wq : ((proj == 1) ? Wk : Wv);
        Bt[i] = (_Float16)W[er * 512 + k];
    } else if (bid < 20480) {
        int i = (bid - 19456) * 256 + tid;
        WoH[i] = (_Float16)Wo[i];
    } else if (bid < 20496) {
        int p = (bid - 20480) * 256 + tid;      // 4096
        double th = -2.0 * 3.14159265358979323846 * (double)p / 4096.0;
        tw[p] = make_float2((float)cos(th), (float)sin(th));
    } else {
        int i = (bid - 20496) * 256 + tid;      // 1536
        bias[i] = (i < 512) ? bq[i] : ((i < 1024) ? bk[i - 512] : bv[i - 1024]);
    }
}

// ---------- GEMM: C = A * Bt^T (+bias), fp16, K=512, 8-phase-class schedule ----------
// 256x256 tile, BK=64 (2 k-halves of 32), 512 threads = 8 waves (2M x 4N),
// per-wave 128x64 (acc[8][4]). LDS = 2 dbuf slots x 4 sub-buffers
// {A.kk0, A.kk1, B.kk0, B.kk1} x 16KB = 128 KB.
// Per K-tile T: 4 phases F(kk, mhalf), each = {4-or-8 ds_read_b128 frags,
// stage ONE sub-buffer (2 x global_load_lds), s_barrier, 16 MFMA (setprio),
// s_barrier}. Staging: F0->[T+1].A.kk1, F1->[T+1].B.kk1, F2->[T+2].A.kk0,
// F3->[T+2].B.kk0. Counted vmcnt(8) before bar2 of F1/F3; tail peels 8->4->0.
// k-order per accumulator unchanged (kk0 then kk1, tiles ascending) ->
// bit-identical results. Verified 319.5us-total config (R2/R3), 71.7-73.5us.
template <int MODE>
__global__ __launch_bounds__(512, 2) void gemm_f16_kernel(
    const _Float16* __restrict__ A, const _Float16* __restrict__ Bt,
    const float* __restrict__ bias,
    _Float16* __restrict__ qT, _Float16* __restrict__ kT,
    _Float16* __restrict__ vout, float* __restrict__ Cout)
{
    constexpr int NBLK   = (MODE == 0) ? 6 : 2;
    constexpr int PERXCD = (MODE == 0) ? 96 : 32;
    __shared__ _Float16 smem[65536];   // 2 x 64KB slots

    const int gi = (blockIdx.x & 7) * PERXCD + (blockIdx.x >> 3);
    const int mb = gi / NBLK;
    const int nb = gi - mb * NBLK;
    const int m0 = mb * 256, n0 = nb * 256;
    const int tid = threadIdx.x;
    const int wave = tid >> 6, lane = tid & 63;
    const int lane15 = lane & 15, quad = lane >> 4;
    const int wmr = (wave >> 2) * 128;
    const int wnr = (wave & 3) * 64;

    const int r0 = tid >> 2;                           // load0 row; load1 = +128
    const int c0 = (tid & 3) ^ ((tid >> 3) & 3);       // swizzled k-chunk (both loads)
    const char* gA = (const char*)A  + ((size_t)(m0 + r0)) * 1024 + c0 * 16;
    const char* gB = (const char*)Bt + ((size_t)(n0 + r0)) * 1024 + c0 * 16;
    const int sbw = wave * 1024;                       // wave-uniform LDS base (load0); load1 = +8192
    const int coloff = (quad ^ ((lane15 >> 1) & 3)) << 4;

    f32x4 acc[8][4];
#pragma unroll
    for (int mi = 0; mi < 8; mi++)
#pragma unroll
        for (int ni = 0; ni < 4; ni++)
#pragma unroll
            for (int r = 0; r < 4; r++) acc[mi][ni][r] = 0.f;

    auto STAGE = [&](int slot, int tensor, int kk, int kt) {
        const char* g = (tensor == 0 ? gA : gB) + kt * 128 + kk * 64;
        char* base = (char*)smem + slot * 65536 + tensor * 32768 + kk * 16384 + sbw;
        __builtin_amdgcn_global_load_lds((const AS1 void*)g, (AS3 void*)base, 16, 0, 0);
        __builtin_amdgcn_global_load_lds((const AS1 void*)(g + 131072), (AS3 void*)(base + 8192), 16, 0, 0);
    };

    half8 af[4], bf[4];
    auto LOADA = [&](int slot, int kk, int mh) {
        const char* ba = (const char*)smem + slot * 65536 + kk * 16384;
#pragma unroll
        for (int j = 0; j < 4; j++)
            af[j] = *(const half8*)(ba + (wmr + (mh * 4 + j) * 16 + lane15) * 64 + coloff);
    };
    auto LOADB = [&](int slot, int kk) {
        const char* bb = (const char*)smem + slot * 65536 + 32768 + kk * 16384;
#pragma unroll
        for (int j = 0; j < 4; j++)
            bf[j] = *(const half8*)(bb + (wnr + j * 16 + lane15) * 64 + coloff);
    };
    auto MMA = [&](int mh) {
        __builtin_amdgcn_s_setprio(1);
#pragma unroll
        for (int j = 0; j < 4; j++)
#pragma unroll
            for (int ni = 0; ni < 4; ni++)
                acc[mh * 4 + j][ni] =
                    __builtin_amdgcn_mfma_f32_16x16x32_f16(af[j], bf[ni], acc[mh * 4 + j][ni], 0, 0, 0);
        __builtin_amdgcn_s_setprio(0);
    };
#define BAR() do { __builtin_amdgcn_s_barrier(); asm volatile("" ::: "memory"); } while (0)
#define VMW(n) asm volatile("s_waitcnt vmcnt(" #n ")" ::: "memory")

    // prologue: [0].kk0 pair, [0].kk1 pair, [1].kk0 pair (12 loads); land [0].kk0.
    STAGE(0, 0, 0, 0); STAGE(0, 1, 0, 0);
    STAGE(0, 0, 1, 0); STAGE(0, 1, 1, 0);
    STAGE(1, 0, 0, 1); STAGE(1, 1, 0, 1);
    VMW(8);
    BAR();

    // K = 512 -> 8 K-tiles of 64. Steady tiles 0..5; peel 6, 7.
    for (int t = 0; t < 6; ++t) {
        const int slot = t & 1, nslot = slot ^ 1;
        // F0 (kk0, mh0)
        LOADA(slot, 0, 0); LOADB(slot, 0);
        STAGE(nslot, 0, 1, t + 1);
        BAR(); MMA(0); BAR();
        // F1 (kk0, mh1) — bf reused
        LOADA(slot, 0, 1);
        STAGE(nslot, 1, 1, t + 1);
        BAR(); MMA(1);
        VMW(8);                       // lands [t].kk1 -> guards F2 reads
        BAR();
        // F2 (kk1, mh0)
        LOADA(slot, 1, 0); LOADB(slot, 1);
        STAGE(slot, 0, 0, t + 2);
        BAR(); MMA(0); BAR();
        // F3 (kk1, mh1)
        LOADA(slot, 1, 1);
        STAGE(slot, 1, 0, t + 2);
        BAR(); MMA(1);
        VMW(8);                       // lands [t+1].kk0 -> guards next F0 reads
        BAR();
    }
    // t = 6 (slot 0): stage only [7].kk1; drain to 4
    LOADA(0, 0, 0); LOADB(0, 0); STAGE(1, 0, 1, 7); BAR(); MMA(0); BAR();
    LOADA(0, 0, 1);              STAGE(1, 1, 1, 7); BAR(); MMA(1);
    VMW(8); BAR();
    LOADA(0, 1, 0); LOADB(0, 1); BAR(); MMA(0); BAR();
    LOADA(0, 1, 1);              BAR(); MMA(1);
    VMW(4);                       // lands [7].kk0
    BAR();
    // t = 7 (slot 1): no stages; drain to 0 before kk1 reads
    LOADA(1, 0, 0); LOADB(1, 0); BAR(); MMA(0); BAR();
    LOADA(1, 0, 1);              BAR(); MMA(1);
    VMW(0);                       // lands [7].kk1
    BAR();
    LOADA(1, 1, 0); LOADB(1, 1); BAR(); MMA(0); BAR();
    LOADA(1, 1, 1);              BAR(); MMA(1);
#undef BAR
#undef VMW

    // ---- epilogue ----
    if (MODE == 1) {
#pragma unroll
        for (int mi = 0; mi < 8; mi++)
#pragma unroll
            for (int ni = 0; ni < 4; ni++) {
                const int n = n0 + wnr + ni * 16 + lane15;
                const float bb = bias[n];
#pragma unroll
                for (int r = 0; r < 4; r++) {
                    const int m = m0 + wmr + mi * 16 + quad * 4 + r;
                    Cout[(size_t)m * 512 + n] = acc[mi][ni][r] + bb;
                }
            }
        return;
    }
    const int proj = n0 >> 9;
    if (proj == 2) {   // V -> fp16 (B,H,L,D)
#pragma unroll
        for (int mi = 0; mi < 8; mi++)
#pragma unroll
            for (int ni = 0; ni < 4; ni++) {
                const int n = n0 + wnr + ni * 16 + lane15;
                const int er = n - 1024, h = er >> 6, d = er & 63;
                const float bb = bias[n];
#pragma unroll
                for (int r = 0; r < 4; r++) {
                    const int m = m0 + wmr + mi * 16 + quad * 4 + r;
                    const int b = m >> 12, l = m & 4095;
                    vout[((size_t)((b * 8 + h) * 4096 + l)) * 64 + d] = (_Float16)(acc[mi][ni][r] + bb);
                }
            }
        return;
    }
    // Q/K: packed-fp16 transposed stores. Lane holds 4 consecutive l (quad*4+r).
    _Float16* dst = (proj == 0) ? qT : kT;
    const int b = m0 >> 12;
    const int lbase = (m0 & 4095) + wmr + quad * 4;
#pragma unroll
    for (int mi = 0; mi < 8; mi++)
#pragma unroll
        for (int ni = 0; ni < 4; ni++) {
            const int e = n0 + wnr + ni * 16 + lane15;
            const int er = e & 511, h = er >> 6, d = er & 63;
            const float bb = bias[e];
            half4v o;
            o[0] = (_Float16)(acc[mi][ni][0] + bb);
            o[1] = (_Float16)(acc[mi][ni][1] + bb);
            o[2] = (_Float16)(acc[mi][ni][2] + bb);
            o[3] = (_Float16)(acc[mi][ni][3] + bb);
            *(half4v*)(dst + ((size_t)((b * 8 + h) * 64 + d)) * 4096 + lbase + mi * 16) = o;
        }
}

// ---------- FFT: 4096-pt, radix-16 (in-register DFT-16), in-place 32KB LDS ----------
__device__ __forceinline__ float2 cmul(float2 a, float2 b) {
    return make_float2(a.x * b.x - a.y * b.y, a.x * b.y + a.y * b.x);
}
__device__ __forceinline__ float2 cmulc(float2 a, float cr, float ci) {
    return make_float2(a.x * cr - a.y * ci, a.x * ci + a.y * cr);
}
__device__ __forceinline__ int swz(int i) { return i ^ ((i >> 4) & 15); }

__device__ __forceinline__ void dft16(float2 x[16]) {
    constexpr float wc[10] = {1.f, 0.92387953f, 0.70710678f, 0.38268343f, 0.f,
                              0.f, -0.70710678f, 0.f, 0.f, -0.92387953f};
    constexpr float wsn[10] = {0.f, -0.38268343f, -0.70710678f, -0.92387953f, -1.f,
                               0.f, -0.70710678f, 0.f, 0.f, 0.38268343f};
    float2 t[16];
#pragma unroll
    for (int u = 0; u < 4; u++) {
        const float2 a = x[u], b = x[u + 4], c = x[u + 8], d = x[u + 12];
        const float2 Ea = make_float2(a.x + c.x, a.y + c.y);
        const float2 Oa = make_float2(a.x - c.x, a.y - c.y);
        const float2 Eb = make_float2(b.x + d.x, b.y + d.y);
        const float2 Ob = make_float2(b.x - d.x, b.y - d.y);
        const float2 y0 = make_float2(Ea.x + Eb.x, Ea.y + Eb.y);
        const float2 y1 = make_float2(Oa.x + Ob.y, Oa.y - Ob.x);
        const float2 y2 = make_float2(Ea.x - Eb.x, Ea.y - Eb.y);
        const float2 y3 = make_float2(Oa.x - Ob.y, Oa.y + Ob.x);
        t[4 * u + 0] = y0;
        t[4 * u + 1] = cmulc(y1, wc[u * 1], wsn[u * 1]);
        t[4 * u + 2] = cmulc(y2, wc[u * 2], wsn[u * 2]);
        t[4 * u + 3] = cmulc(y3, wc[u * 3], wsn[u * 3]);
    }
#pragma unroll
    for (int v = 0; v < 4; v++) {
        const float2 a = t[v], b = t[v + 4], c = t[v + 8], d = t[v + 12];
        const float2 Ea = make_float2(a.x + c.x, a.y + c.y);
        const float2 Oa = make_float2(a.x - c.x, a.y - c.y);
        const float2 Eb = make_float2(b.x + d.x, b.y + d.y);
        const float2 Ob = make_float2(b.x - d.x, b.y - d.y);
        x[v]      = make_float2(Ea.x + Eb.x, Ea.y + Eb.y);
        x[v + 4]  = make_float2(Oa.x + Ob.y, Oa.y - Ob.x);
        x[v + 8]  = make_float2(Ea.x - Eb.x, Ea.y - Eb.y);
        x[v + 12] = make_float2(Oa.x - Ob.y, Oa.y + Ob.x);
    }
}

__device__ __forceinline__ void fft4096_r16(float2* buf, const float2* __restrict__ tw,
                                            int tid, float2 (&x)[16]) {
    __syncthreads();
#pragma unroll
    for (int j = 0; j < 16; j++) x[j] = buf[swz(tid + 256 * j)];
    __syncthreads();
    dft16(x);
    buf[swz(16 * tid)] = x[0];
#pragma unroll
    for (int m = 1; m < 16; m++) buf[swz(16 * tid + m)] = cmul(x[m], tw[tid * m]);
    __syncthreads();
#pragma unroll
    for (int j = 0; j < 16; j++) x[j] = buf[swz(tid + 256 * j)];
    __syncthreads();
    dft16(x);
    {
        const int q = tid & 15, p = tid >> 4;
        const int base = q + 256 * p;
        buf[swz(base)] = x[0];
#pragma unroll
        for (int m = 1; m < 16; m++)
            buf[swz(base + 16 * m)] = cmul(x[m], tw[(p * m) << 4]);
    }
    __syncthreads();
#pragma unroll
    for (int j = 0; j < 16; j++) x[j] = buf[swz(tid + 256 * j)];
    __syncthreads();
    dft16(x);
#pragma unroll
    for (int m = 0; m < 16; m++) buf[swz(tid + 256 * m)] = x[m];
    __syncthreads();
}

__global__ __launch_bounds__(256) void fft_partial_kernel(
    const _Float16* __restrict__ qT, const _Float16* __restrict__ kT,
    const float2* __restrict__ tw, float2* __restrict__ spec)
{
    __shared__ float2 buf[4096];
    const int tid = threadIdx.x;
    const int bh = blockIdx.x >> 4, chunk = blockIdx.x & 15;
    float sx[16], sy[16];
#pragma unroll
    for (int i = 0; i < 16; i++) { sx[i] = 0.f; sy[i] = 0.f; }
    const _Float16* qb = qT + (size_t)bh * 64 * 4096;
    const _Float16* kb = kT + (size_t)bh * 64 * 4096;
    float2 x[16];
    for (int dd = 0; dd < 4; dd++) {
        const int d = chunk * 4 + dd;
#pragma unroll
        for (int i = 0; i < 2; i++) {
            const int t0 = 2048 * i + tid * 8;
            const half8 fq = *(const half8*)(qb + d * 4096 + t0);
            const half8 fk = *(const half8*)(kb + d * 4096 + t0);
#pragma unroll
            for (int j = 0; j < 8; j++)
                buf[swz(t0 + j)] = make_float2((float)fq[j], (float)fk[j]);
        }
        fft4096_r16(buf, tw, tid, x);
#pragma unroll
        for (int i = 0; i < 16; i++) {
            const int f = tid + 256 * i;
            const float2 Zf = x[i];
            const float2 Zm = buf[swz((4096 - f) & 4095)];
            const float Qr  = 0.5f * (Zf.x + Zm.x);
            const float Qi  = 0.5f * (Zf.y - Zm.y);
            const float cKr = 0.5f * (Zf.y + Zm.y);
            const float cKi = 0.5f * (Zf.x - Zm.x);
            sx[i] += Qr * cKr - Qi * cKi;
            sy[i] += Qr * cKi + Qi * cKr;
        }
        __syncthreads();
    }
    float2* out = spec + (size_t)blockIdx.x * 4096;
#pragma unroll
    for (int i = 0; i < 16; i++) out[tid + 256 * i] = make_float2(sx[i], sy[i]);
}

// ---------- sum of 16 partial spectra (+conj), vectorized float4 ----------
__global__ __launch_bounds__(256) void sum_spec_kernel(
    const float4* __restrict__ spec4, float4* __restrict__ ssum4)
{
    const int bh = blockIdx.x >> 3;
    const int i4 = (blockIdx.x & 7) * 256 + threadIdx.x;
    const float4* base = spec4 + (size_t)bh * 16 * 2048 + i4;
    float4 s = make_float4(0.f, 0.f, 0.f, 0.f);
#pragma unroll
    for (int c = 0; c < 16; c++) {
        const float4 v = base[(size_t)c * 2048];
        s.x += v.x; s.y += v.y; s.z += v.z; s.w += v.w;
    }
    s.y = -s.y; s.w = -s.w;   // conj
    ssum4[(size_t)bh * 2048 + i4] = s;
}

// per block: one (b,h). corr = Re(FFT(conj(S))); top-8 + softmax (serial merge,
// R2/R3-verified form).
__global__ __launch_bounds__(256) void reduce_topk_kernel(
    const float2* __restrict__ ssum, const float2* __restrict__ tw,
    int* __restrict__ top_idx, float* __restrict__ top_w)
{
    __shared__ float2 buf[4096];
    __shared__ float wv[4];
    __shared__ int wi[4];
    const int tid = threadIdx.x;
    const int bh = blockIdx.x;
#pragma unroll
    for (int i = 0; i < 16; i++) {
        const int f = tid + 256 * i;
        buf[swz(f)] = ssum[(size_t)bh * 4096 + f];
    }
    float2 x[16];
    fft4096_r16(buf, tw, tid, x);
    float vals[8]; int idxs[8];
    for (int k = 0; k < 8; k++) {
        float best = -3.0e38f; int bi = 0;
#pragma unroll
        for (int i = 0; i < 16; i++) {
            const int f = tid + 256 * i;
            const float c = buf[swz(f)].x;
            if (c > best) { best = c; bi = f; }
        }
#pragma unroll
        for (int off = 32; off > 0; off >>= 1) {
            const float ov = __shfl_down(best, off);
            const int oi = __shfl_down(bi, off);
            if (ov > best || (ov == best && oi < bi)) { best = ov; bi = oi; }
        }
        if ((tid & 63) == 0) { wv[tid >> 6] = best; wi[tid >> 6] = bi; }
        __syncthreads();
        if (tid == 0) {
            best = wv[0]; bi = wi[0];
            for (int w = 1; w < 4; w++) {
                if (wv[w] > best || (wv[w] == best && wi[w] < bi)) { best = wv[w]; bi = wi[w]; }
            }
            vals[k] = best; idxs[k] = bi;
            buf[swz(bi)].x = -3.4e38f;
        }
        __syncthreads();
    }
    if (tid == 0) {
        const float scale = 1.f / (4096.f * 64.f);
        float e[8], s = 0.f;
        const float mx = vals[0] * scale;
        for (int k = 0; k < 8; k++) { e[k] = __expf(vals[k] * scale - mx); s += e[k]; }
        for (int k = 0; k < 8; k++) {
            top_w[bh * 8 + k] = e[k] / s;
            top_idx[bh * 8 + k] = idxs[k];
        }
    }
}

// ---------- gather: out_pre[b,l,h*64+d] = sum_k w_k * v[b,h,(l+idx_k)%L,d] ----------
// XCD-affinity swizzle (R2/R3-verified form): all 128 blocks of one bh land on
// one XCD; 8 bh/XCD = 4 MB = one L2. k-ascending accumulation -> bit-identical.
__global__ __launch_bounds__(256) void gather_kernel(
    const half8* __restrict__ v8, const int* __restrict__ top_idx,
    const float* __restrict__ top_w, half8* __restrict__ out8)
{
    const int gi = (blockIdx.x & 7) * 1024 + (blockIdx.x >> 3);  // 8192 blocks, bijective
    const int bh = gi >> 7;
    const int lgrp = gi & 127;
    const int b = bh >> 3, h = bh & 7;
    const int tid = threadIdx.x;
    const int l = lgrp * 32 + (tid >> 3);
    const int d8 = tid & 7;
    int idx[8]; float w[8];
#pragma unroll
    for (int k = 0; k < 8; k++) { idx[k] = top_idx[bh * 8 + k]; w[k] = top_w[bh * 8 + k]; }
    const half8* vb = v8 + (size_t)bh * 4096 * 8;
    float a[8];
#pragma unroll
    for (int j = 0; j < 8; j++) a[j] = 0.f;
#pragma unroll
    for (int k = 0; k < 8; k++) {
        const int ls = (l + idx[k]) & 4095;
        const half8 pv = vb[(size_t)ls * 8 + d8];
#pragma unroll
        for (int j = 0; j < 8; j++) a[j] += w[k] * (float)pv[j];
    }
    half8 o;
#pragma unroll
    for (int j = 0; j < 8; j++) o[j] = (_Float16)a[j];
    out8[((size_t)(b * 4096 + l)) * 64 + h * 8 + d8] = o;
}

// ---------- host ----------
extern "C" void kernel_launch(void* const* d_in, const int* in_sizes, int n_in,
                              void* d_out, int out_size, void* d_ws, size_t ws_size,
                              hipStream_t stream) {
    (void)in_sizes; (void)n_in; (void)out_size; (void)ws_size;
    const float* x  = (const float*)d_in[0];
    const float* Wq = (const float*)d_in[1];
    const float* bq = (const float*)d_in[2];
    const float* Wk = (const float*)d_in[3];
    const float* bk = (const float*)d_in[4];
    const float* Wv = (const float*)d_in[5];
    const float* bv = (const float*)d_in[6];
    const float* Wo = (const float*)d_in[7];
    const float* bo = (const float*)d_in[8];
    float* out = (float*)d_out;

    char* ws = (char*)d_ws;
    size_t off = 0;
    auto alloc = [&](size_t bytes) -> void* {
        void* p = ws + off; off += (bytes + 255) & ~(size_t)255; return p;
    };
    _Float16* xh   = (_Float16*)alloc(33554432);   // 32768x512 fp16
    _Float16* qT   = (_Float16*)alloc(33554432);   // (B,H,D,L) fp16
    _Float16* kT   = (_Float16*)alloc(33554432);
    _Float16* vbuf = (_Float16*)alloc(33554432);   // (B,H,L,D) fp16
    float2* spec   = (float2*)alloc(33554432);     // 1024 x 4096 float2
    float2* ssum   = (float2*)alloc(2097152);      // 64 x 4096 float2 (summed, conj)
    _Float16* BtH  = (_Float16*)alloc(1572864);    // 1536x512 fp16
    _Float16* WoH  = (_Float16*)alloc(524288);     // 512x512 fp16
    float* biasQKV = (float*)alloc(6144);          // 1536 fp32
    float2* tw     = (float2*)alloc(32768);        // 4096 twiddles
    int*   top_idx = (int*)alloc(2048);
    float* top_w   = (float*)alloc(2048);
    _Float16* out_pre = xh;                        // alias: xh dead after GEMM1

    prep_all_kernel<<<20502, 256, 0, stream>>>(x, Wq, Wk, Wv, Wo, bq, bk, bv,
                                               xh, BtH, WoH, tw, biasQKV);
    gemm_f16_kernel<0><<<768, 512, 0, stream>>>(xh, BtH, biasQKV, qT, kT, vbuf, nullptr);
    fft_partial_kernel<<<1024, 256, 0, stream>>>(qT, kT, tw, spec);
    sum_spec_kernel<<<512, 256, 0, stream>>>((const float4*)spec, (float4*)ssum);
    reduce_topk_kernel<<<64, 256, 0, stream>>>(ssum, tw, top_idx, top_w);
    gather_kernel<<<8192, 256, 0, stream>>>((const half8*)vbuf, top_idx, top_w,
                                            (half8*)out_pre);
    gemm_f16_kernel<1><<<256, 512, 0, stream>>>(out_pre, WoH, bo, nullptr, nullptr, nullptr, out);
}